// Round 8
// baseline (2679.002 us; speedup 1.0000x reference)
//
#include <hip/hip_runtime.h>
#include <stdint.h>
#include <math.h>

typedef short short8 __attribute__((ext_vector_type(8)));
typedef float floatx4 __attribute__((ext_vector_type(4)));

#define MFMA(a, b, c) __builtin_amdgcn_mfma_f32_16x16x32_bf16((a), (b), (c), 0, 0, 0)

#define B_   64
#define S_   256
#define DIN  512
#define DH   1024
#define G3   3072
#define DOUT 64
#define M_   (B_ * S_)  // 16384
#define WPAD 1032       // 1024 + 8 bf16 pad: row stride 2064B = 516 words, %32=4 -> 2-way (free)

#define AGENT_LD_U64(p) __hip_atomic_load((p), __ATOMIC_RELAXED, __HIP_MEMORY_SCOPE_AGENT)
#define AGENT_ST_U32(p, v) __hip_atomic_store((p), (v), __ATOMIC_RELAXED, __HIP_MEMORY_SCOPE_AGENT)

__device__ __forceinline__ unsigned short f2bf(float f) {
    union { float f; uint32_t u; } v; v.f = f;
    uint32_t u = v.u;
    uint32_t r = (u + 0x7fffu + ((u >> 16) & 1u)) >> 16;  // RNE
    return (unsigned short)r;
}
__device__ __forceinline__ float bf2f(unsigned short s) {
    union { uint32_t u; float f; } v; v.u = ((uint32_t)s) << 16; return v.f;
}
__device__ __forceinline__ short8 ld8(const unsigned short* p) {
    return *reinterpret_cast<const short8*>(p);
}
__device__ __forceinline__ float fast_sigmoid(float x) {
    return 1.f / (1.f + __expf(-x));
}
__device__ __forceinline__ float fast_tanh(float x) {
    return 1.f - 2.f / (__expf(2.f * x) + 1.f);
}

// ---------------- elementwise: fp32 -> bf16 cast ----------------
__global__ void cast_bf16_kernel(const float* __restrict__ src,
                                 unsigned short* __restrict__ dst, int n) {
    int i = blockIdx.x * 256 + threadIdx.x;
    if (i < n) dst[i] = f2bf(src[i]);
}

// ---------------- embedding gather into [s*64+b][512] bf16 ----------------
__global__ void gather_kernel(const int* __restrict__ x, const float* __restrict__ emb,
                              unsigned short* __restrict__ xe) {
    int g = blockIdx.x * 256 + threadIdx.x;  // 16384*512 total
    int m = g >> 9;          // row = s*64+b
    int k = g & 511;
    int s = m >> 6, b = m & 63;
    int tok = x[b * S_ + s];
    xe[(size_t)m * DIN + k] = f2bf(emb[(size_t)tok * DIN + k]);
}

// ---------------- bt-GEMM: C[M,N] bf16 = A[M,K] @ W[N,K]^T + bias ----------------
__global__ __launch_bounds__(256) void gemm_bt_bias(
        const unsigned short* __restrict__ A, const unsigned short* __restrict__ W,
        const float* __restrict__ bias, unsigned short* __restrict__ C,
        int M, int N, int K) {
    __shared__ __align__(16) unsigned short As[128 * 32];
    __shared__ __align__(16) unsigned short Ws[128 * 32];
    int tid = threadIdx.x;
    int lane = tid & 63, wv = tid >> 6;
    int wm = wv >> 1, wn = wv & 1;
    int q = lane >> 4, l15 = lane & 15;
    int bm = blockIdx.x, bn = blockIdx.y;

    floatx4 acc[4][4];
    floatx4 z = {0.f, 0.f, 0.f, 0.f};
    for (int i = 0; i < 4; i++) for (int j = 0; j < 4; j++) acc[i][j] = z;

    int row_s = tid >> 1;
    int col_s = (tid & 1) * 16;
    const unsigned short* Ab = A + (size_t)(bm * 128 + row_s) * K + col_s;
    const unsigned short* Wb = W + (size_t)(bn * 128 + row_s) * K + col_s;
    unsigned short* AsW = &As[row_s * 32 + col_s];
    unsigned short* WsW = &Ws[row_s * 32 + col_s];

    for (int k0 = 0; k0 < K; k0 += 32) {
        __syncthreads();
        *reinterpret_cast<short8*>(AsW)     = ld8(Ab + k0);
        *reinterpret_cast<short8*>(AsW + 8) = ld8(Ab + k0 + 8);
        *reinterpret_cast<short8*>(WsW)     = ld8(Wb + k0);
        *reinterpret_cast<short8*>(WsW + 8) = ld8(Wb + k0 + 8);
        __syncthreads();
        short8 af[4], wf[4];
        for (int t = 0; t < 4; t++) {
            af[t] = ld8(&As[(wm * 64 + t * 16 + l15) * 32 + q * 8]);
            wf[t] = ld8(&Ws[(wn * 64 + t * 16 + l15) * 32 + q * 8]);
        }
        for (int i = 0; i < 4; i++)
            for (int j = 0; j < 4; j++)
                acc[i][j] = MFMA(af[i], wf[j], acc[i][j]);
    }
    for (int i = 0; i < 4; i++) {
        int row = bm * 128 + wm * 64 + i * 16 + q * 4;
        for (int j = 0; j < 4; j++) {
            int col = bn * 128 + wn * 64 + j * 16 + l15;
            float bv = bias[col];
            for (int r = 0; r < 4; r++)
                C[(size_t)(row + r) * N + col] = f2bf(acc[i][j][r] + bv);
        }
    }
}

// ---------------- persistent GRU recurrence: tagged-data exchange ----------------
// 128 blocks (jc 0..63 x mh 0..1) x 128 thr (2 waves, mt 0/1). Wave owns rows
// brow0..+16, cols jc*16..+16, ALL 3 gates, FULL K=1024 (w_hh slice in LDS, 96KB,
// padded rows). h stored as tagged u32 (step+1)<<16 | bf16(h) via relaxed
// agent stores (fire-and-forget). Consumers agent-load the tagged words and
// retry until every tag matches -> no drains, no flags, no barriers, no LDS
// handoff in the step loop. ws poison 0xAAAA can't collide with tags 1..256.
__global__ __launch_bounds__(128, 1) void gru_persistent(
        const unsigned short* __restrict__ gi,   // [256][64][3072] bf16 (incl b_ih)
        const unsigned short* __restrict__ whh,  // [3072][1024] bf16
        const float* __restrict__ b_hh,          // [3072]
        uint32_t* __restrict__ hst) {            // [256*64][1024] tagged u32
    const int tid = threadIdx.x;
    const int lane = tid & 63, mt = tid >> 6;
    const int q = lane >> 4, l15 = lane & 15;
    const int jc = blockIdx.x >> 1, mh = blockIdx.x & 1;
    const int j = jc * 16 + l15;                 // output h-col
    const int brow0 = mh * 32 + mt * 16;         // wave's 16 batch rows
    const int myrow = brow0 + l15;               // A-frag row this lane reads

    __shared__ __align__(16) unsigned short Ws[3 * 16 * WPAD];  // 96.75 KB

    // ---- preload w_hh slice: 48 rows (g*16+r16) x 1024 shorts, in 8-short units ----
    for (int u = tid; u < 6144; u += 128) {      // 48 rows x 128 units/row
        int row = u >> 7;                        // 0..47 = g*16 + r16
        int kc  = (u & 127) * 8;                 // 0..1016 step 8
        int g = row >> 4, r16 = row & 15;
        *reinterpret_cast<short8*>(&Ws[row * WPAD + kc]) =
            ld8(whh + (size_t)(g * 1024 + jc * 16 + r16) * DH + kc);
    }
    __syncthreads();

    const float bhr = b_hh[j], bhz = b_hh[1024 + j], bhn = b_hh[2048 + j];
    float hreg[4] = {0.f, 0.f, 0.f, 0.f};
    float gir[4], giz[4], gin[4];
#pragma unroll
    for (int r = 0; r < 4; r++) {
        int b = brow0 + q * 4 + r;
        gir[r] = bf2f(gi[(size_t)b * G3 + j]);
        giz[r] = bf2f(gi[(size_t)b * G3 + 1024 + j]);
        gin[r] = bf2f(gi[(size_t)b * G3 + 2048 + j]);
    }

    for (int s = 0; s < S_; s++) {
        floatx4 zf = {0.f, 0.f, 0.f, 0.f};
        floatx4 acc[3] = {zf, zf, zf};

        if (s > 0) {
            const uint64_t exp2 = ((uint64_t)s << 16) | ((uint64_t)s << 48);
            const uint64_t msk  = 0xffff0000ffff0000ull;
            const uint64_t* hb =
                (const uint64_t*)(hst + ((size_t)(s - 1) * B_ + myrow) * DH);
            for (int c = 0; c < 4; c++) {        // 4 chunks x 8 k-frags
                uint64_t u[32];
                for (;;) {
#pragma unroll
                    for (int t = 0; t < 8; t++) {
                        int k = (c * 8 + t) * 32 + q * 8;
                        const uint64_t* p = hb + (k >> 1);
                        u[t * 4 + 0] = AGENT_LD_U64(p);
                        u[t * 4 + 1] = AGENT_LD_U64(p + 1);
                        u[t * 4 + 2] = AGENT_LD_U64(p + 2);
                        u[t * 4 + 3] = AGENT_LD_U64(p + 3);
                    }
                    uint64_t err = 0;
#pragma unroll
                    for (int t = 0; t < 32; t++) err |= (u[t] ^ exp2);
                    if (__all((err & msk) == 0ull)) break;
                }
#pragma unroll
                for (int t = 0; t < 8; t++) {
                    union { uint32_t w[4]; short8 v; } fr;
#pragma unroll
                    for (int h2 = 0; h2 < 4; h2++) {
                        uint64_t x = u[t * 4 + h2];
                        fr.w[h2] = (uint32_t)(x & 0xffffu) |
                                   ((uint32_t)(x >> 32) << 16);
                    }
                    int kk = c * 8 + t;
#pragma unroll
                    for (int g = 0; g < 3; g++)
                        acc[g] = MFMA(fr.v,
                                      ld8(&Ws[(g * 16 + l15) * WPAD + kk * 32 + q * 8]),
                                      acc[g]);
                }
            }
        }

        // ---- gates + tagged publish (fire-and-forget) ----
        const uint32_t tag = (uint32_t)(s + 1) << 16;
#pragma unroll
        for (int r = 0; r < 4; r++) {
            int b = brow0 + q * 4 + r;
            float rg = fast_sigmoid(gir[r] + acc[0][r] + bhr);
            float zg = fast_sigmoid(giz[r] + acc[1][r] + bhz);
            float ng = fast_tanh(gin[r] + rg * (acc[2][r] + bhn));
            float h = (1.f - zg) * ng + zg * hreg[r];
            hreg[r] = h;
            AGENT_ST_U32(&hst[((size_t)s * B_ + b) * DH + j],
                         tag | (uint32_t)f2bf(h));
        }
        // gi prefetch for s+1 (off the critical chain; overlaps next MFMA phase)
        if (s + 1 < S_) {
            const unsigned short* gp = gi + (size_t)(s + 1) * B_ * G3;
#pragma unroll
            for (int r = 0; r < 4; r++) {
                int b = brow0 + q * 4 + r;
                gir[r] = bf2f(gp[(size_t)b * G3 + j]);
                giz[r] = bf2f(gp[(size_t)b * G3 + 1024 + j]);
                gin[r] = bf2f(gp[(size_t)b * G3 + 2048 + j]);
            }
        }
    }
}

// ---------------- FC + log_softmax, fused (reads tagged hs) ----------------
__global__ __launch_bounds__(256) void fc_logsoftmax(
        const uint32_t* __restrict__ hst,         // [16384][1024] tagged u32
        const unsigned short* __restrict__ fcw,   // [64][1024] bf16
        const float* __restrict__ fcb,            // [64]
        float* __restrict__ out) {                // [B][S][64]
    int tid = threadIdx.x;
    int lane = tid & 63, mt = tid >> 6;
    int q = lane >> 4, l15 = lane & 15;
    int r0 = blockIdx.x * 64;

    floatx4 acc[4];
    floatx4 z = {0.f, 0.f, 0.f, 0.f};
    for (int nt = 0; nt < 4; nt++) acc[nt] = z;

    const uint64_t* Ap = (const uint64_t*)hst +
        (((size_t)(r0 + mt * 16 + l15)) * DH + q * 8) / 2;
    const unsigned short* Wp = fcw + (size_t)l15 * DH + q * 8;
    for (int k0 = 0; k0 < DH; k0 += 32) {
        union { uint32_t w[4]; short8 v; } fr;
        const uint64_t* p = Ap + (k0 >> 1);
#pragma unroll
        for (int h2 = 0; h2 < 4; h2++) {
            uint64_t x = p[h2];
            fr.w[h2] = (uint32_t)(x & 0xffffu) | ((uint32_t)(x >> 32) << 16);
        }
        for (int nt = 0; nt < 4; nt++)
            acc[nt] = MFMA(fr.v, ld8(Wp + (size_t)nt * 16 * DH + k0), acc[nt]);
    }

    float bv[4];
    for (int nt = 0; nt < 4; nt++) bv[nt] = fcb[nt * 16 + l15];

    for (int r = 0; r < 4; r++) {
        float v[4];
        for (int nt = 0; nt < 4; nt++) v[nt] = acc[nt][r] + bv[nt];
        float m = fmaxf(fmaxf(v[0], v[1]), fmaxf(v[2], v[3]));
        for (int off = 1; off < 16; off <<= 1) m = fmaxf(m, __shfl_xor(m, off));
        float se = __expf(v[0] - m) + __expf(v[1] - m) + __expf(v[2] - m) + __expf(v[3] - m);
        for (int off = 1; off < 16; off <<= 1) se += __shfl_xor(se, off);
        float L = logf(se);
        int row = r0 + mt * 16 + q * 4 + r;  // = s*64 + b
        int srow = row >> 6, brow = row & 63;
        float* op = out + (size_t)(brow * S_ + srow) * DOUT;
        for (int nt = 0; nt < 4; nt++) op[nt * 16 + l15] = v[nt] - m - L;
    }
}

extern "C" void kernel_launch(void* const* d_in, const int* in_sizes, int n_in,
                              void* d_out, int out_size, void* d_ws, size_t ws_size,
                              hipStream_t stream) {
    const int*   x    = (const int*)d_in[0];
    const float* emb  = (const float*)d_in[1];
    const float* w_ih = (const float*)d_in[2];
    const float* w_hh = (const float*)d_in[3];
    const float* b_ih = (const float*)d_in[4];
    const float* b_hh = (const float*)d_in[5];
    const float* fc_w = (const float*)d_in[6];
    const float* fc_b = (const float*)d_in[7];
    float* out = (float*)d_out;

    char* p = (char*)d_ws;
    uint32_t*       hst   = (uint32_t*)p;       p += (size_t)M_ * DH * 4;    // 67.1 MB tagged
    unsigned short* xe    = (unsigned short*)p; p += (size_t)M_ * DIN * 2;   // 16 MB
    unsigned short* gi    = (unsigned short*)p; p += (size_t)M_ * G3 * 2;    // 100.7 MB
    unsigned short* wih_b = (unsigned short*)p; p += (size_t)G3 * DIN * 2;   // 3 MB
    unsigned short* whh_b = (unsigned short*)p; p += (size_t)G3 * DH * 2;    // 6.3 MB
    unsigned short* fcw_b = (unsigned short*)p; p += (size_t)DOUT * DH * 2;  // 128 KB

    cast_bf16_kernel<<<(G3 * DIN + 255) / 256, 256, 0, stream>>>(w_ih, wih_b, G3 * DIN);
    cast_bf16_kernel<<<(G3 * DH + 255) / 256, 256, 0, stream>>>(w_hh, whh_b, G3 * DH);
    cast_bf16_kernel<<<(DOUT * DH + 255) / 256, 256, 0, stream>>>(fc_w, fcw_b, DOUT * DH);
    gather_kernel<<<(M_ * DIN) / 256, 256, 0, stream>>>(x, emb, xe);

    gemm_bt_bias<<<dim3(M_ / 128, G3 / 128), 256, 0, stream>>>(
        xe, wih_b, b_ih, gi, M_, G3, DIN);

    gru_persistent<<<128, 128, 0, stream>>>(gi, whh_b, b_hh, hst);

    fc_logsoftmax<<<M_ / 64, 256, 0, stream>>>(hst, fcw_b, fc_b, out);
}